// Round 2
// baseline (399.814 us; speedup 1.0000x reference)
//
#include <hip/hip_runtime.h>

// HistogramLoss: B=16, C=3, H=W=1024, num_bins=256.
// loss = mean over (48 rows x 256 bins) of |c_out - c_tgt| / (H*W), with
// integer counts c = histogram(floor(x*256) clipped to [0,255]).
// Counts are exact integers -> compute exactly, divide once at the end.

#define NB    256
#define HW_N  (1024 * 1024)
#define ROWS  48               // B*C
#define BLOCKS_PER_ROW 32
#define THREADS 256

// counts layout in d_ws: uint32 [2][ROWS][NB]  (tensor, row, bin)

__global__ __launch_bounds__(THREADS) void hist_kernel(
    const float* __restrict__ out_t,
    const float* __restrict__ tgt_t,
    unsigned int* __restrict__ counts)
{
    __shared__ unsigned int lh[NB];
    const int tid = threadIdx.x;
    for (int i = tid; i < NB; i += THREADS) lh[i] = 0u;
    __syncthreads();

    const int blk = blockIdx.x;                 // 0 .. 2*ROWS*BLOCKS_PER_ROW-1
    const int seg = blk / BLOCKS_PER_ROW;       // 0..95 : tensor*ROWS + row
    const int sub = blk % BLOCKS_PER_ROW;
    const float* src = (seg < ROWS) ? out_t : tgt_t;
    const int row = (seg < ROWS) ? seg : (seg - ROWS);

    const size_t base = (size_t)row * HW_N + (size_t)sub * (HW_N / BLOCKS_PER_ROW);
    const float4* __restrict__ p = reinterpret_cast<const float4*>(src + base);
    const int n4 = HW_N / BLOCKS_PER_ROW / 4;   // 8192 float4 per block

    for (int i = tid; i < n4; i += THREADS) {
        float4 v = p[i];
        int i0 = min(max((int)floorf(v.x * (float)NB), 0), NB - 1);
        int i1 = min(max((int)floorf(v.y * (float)NB), 0), NB - 1);
        int i2 = min(max((int)floorf(v.z * (float)NB), 0), NB - 1);
        int i3 = min(max((int)floorf(v.w * (float)NB), 0), NB - 1);
        atomicAdd(&lh[i0], 1u);
        atomicAdd(&lh[i1], 1u);
        atomicAdd(&lh[i2], 1u);
        atomicAdd(&lh[i3], 1u);
    }
    __syncthreads();

    unsigned int* __restrict__ g = counts + (size_t)seg * NB;
    for (int i = tid; i < NB; i += THREADS) {
        unsigned int c = lh[i];
        if (c) atomicAdd(&g[i], c);
    }
}

__global__ __launch_bounds__(THREADS) void reduce_kernel(
    const unsigned int* __restrict__ counts,
    float* __restrict__ out)
{
    const int tid = threadIdx.x;   // one bin per thread
    long long acc = 0;
    for (int r = 0; r < ROWS; ++r) {
        int a = (int)counts[(size_t)r * NB + tid];
        int b = (int)counts[(size_t)(ROWS + r) * NB + tid];
        int d = a - b;
        acc += (long long)((d < 0) ? -d : d);
    }
    __shared__ long long s[THREADS];
    s[tid] = acc;
    __syncthreads();
    for (int off = THREADS / 2; off >= 1; off >>= 1) {
        if (tid < off) s[tid] += s[tid + off];
        __syncthreads();
    }
    if (tid == 0) {
        double v = (double)s[0] / ((double)HW_N * (double)ROWS * (double)NB);
        out[0] = (float)v;
    }
}

extern "C" void kernel_launch(void* const* d_in, const int* in_sizes, int n_in,
                              void* d_out, int out_size, void* d_ws, size_t ws_size,
                              hipStream_t stream) {
    const float* out_t = (const float*)d_in[0];
    const float* tgt_t = (const float*)d_in[1];
    // d_in[2] = num_bins (always 256 for this problem; hardcoded as NB)
    unsigned int* counts = (unsigned int*)d_ws;
    float* out = (float*)d_out;

    const size_t counts_bytes = (size_t)2 * ROWS * NB * sizeof(unsigned int);
    hipMemsetAsync(counts, 0, counts_bytes, stream);

    dim3 grid(2 * ROWS * BLOCKS_PER_ROW);  // 3072 blocks
    dim3 block(THREADS);
    hist_kernel<<<grid, block, 0, stream>>>(out_t, tgt_t, counts);
    reduce_kernel<<<1, block, 0, stream>>>(counts, out);
}

// Round 3
// 395.911 us; speedup vs baseline: 1.0099x; 1.0099x over previous
//
#include <hip/hip_runtime.h>

// HistogramLoss: B=16, C=3, H=W=1024, num_bins=256.
// loss = sum over (48 rows, 256 bins) |c_out - c_tgt| / (HW * 48 * 256),
// counts are exact integers. Three kernels:
//   1) hist: 1536 blocks, per-wave LDS histograms, unroll x4 loads,
//      non-atomic partial store  partials[seg*16+sub][256]
//   2) row-reduce: 96 blocks, sum 16 sub-block partials, |diff|,
//      block-reduce, one uint atomicAdd per block
//   3) finalize: 1 thread, divide.

#define NB       256
#define HW_N     (1024 * 1024)
#define ROWS     48                  // B*C
#define SEGS     (2 * ROWS)          // 96: tensor*ROWS + row
#define SUBS     16                  // sub-blocks per segment
#define THREADS  256
#define NWAVES   (THREADS / 64)

// d_ws layout:
//   uint32 partials[SEGS*SUBS][NB]   (1536*256*4 = 1.5 MB)
//   uint32 gsum                      (1 value, after partials)

__global__ __launch_bounds__(THREADS) void hist_kernel(
    const float* __restrict__ out_t,
    const float* __restrict__ tgt_t,
    unsigned int* __restrict__ partials)
{
    __shared__ unsigned int lh[NWAVES][NB];
    const int tid = threadIdx.x;
    const int wid = tid >> 6;

    #pragma unroll
    for (int w = 0; w < NWAVES; ++w)
        for (int i = tid; i < NB; i += THREADS) lh[w][i] = 0u;
    __syncthreads();

    const int blk = blockIdx.x;            // 0 .. SEGS*SUBS-1
    const int seg = blk / SUBS;
    const int sub = blk % SUBS;
    const float* src = (seg < ROWS) ? out_t : tgt_t;
    const int row = (seg < ROWS) ? seg : (seg - ROWS);

    const int elems = HW_N / SUBS;         // 65536 per block
    const size_t base = (size_t)row * HW_N + (size_t)sub * elems;
    const float4* __restrict__ p = reinterpret_cast<const float4*>(src + base);
    // 16384 float4 per block; 64 per thread; 16 iters of 4 independent loads.

    unsigned int* __restrict__ h = lh[wid];
    for (int t = 0; t < 16; ++t) {
        const int i0 = t * 1024 + tid;
        float4 a = p[i0];
        float4 b = p[i0 + 256];
        float4 c = p[i0 + 512];
        float4 d = p[i0 + 768];
        #define BIN(x) min(max((int)floorf((x) * (float)NB), 0), NB - 1)
        atomicAdd(&h[BIN(a.x)], 1u); atomicAdd(&h[BIN(a.y)], 1u);
        atomicAdd(&h[BIN(a.z)], 1u); atomicAdd(&h[BIN(a.w)], 1u);
        atomicAdd(&h[BIN(b.x)], 1u); atomicAdd(&h[BIN(b.y)], 1u);
        atomicAdd(&h[BIN(b.z)], 1u); atomicAdd(&h[BIN(b.w)], 1u);
        atomicAdd(&h[BIN(c.x)], 1u); atomicAdd(&h[BIN(c.y)], 1u);
        atomicAdd(&h[BIN(c.z)], 1u); atomicAdd(&h[BIN(c.w)], 1u);
        atomicAdd(&h[BIN(d.x)], 1u); atomicAdd(&h[BIN(d.y)], 1u);
        atomicAdd(&h[BIN(d.z)], 1u); atomicAdd(&h[BIN(d.w)], 1u);
        #undef BIN
    }
    __syncthreads();

    // merge the 4 per-wave histograms and store (non-atomic, block-private slot)
    unsigned int* __restrict__ g = partials + (size_t)blk * NB;
    for (int i = tid; i < NB; i += THREADS) {
        unsigned int c = lh[0][i] + lh[1][i] + lh[2][i] + lh[3][i];
        g[i] = c;
    }
}

__global__ __launch_bounds__(THREADS) void rowdiff_kernel(
    const unsigned int* __restrict__ partials,
    unsigned int* __restrict__ gsum)
{
    const int r = blockIdx.x;      // 0..ROWS-1
    const int bin = threadIdx.x;   // one bin per thread
    unsigned int a = 0, b = 0;
    #pragma unroll
    for (int s = 0; s < SUBS; ++s) {
        a += partials[((size_t)(r)         * SUBS + s) * NB + bin];
        b += partials[((size_t)(ROWS + r)  * SUBS + s) * NB + bin];
    }
    int d = (int)a - (int)b;
    unsigned int ad = (unsigned int)((d < 0) ? -d : d);

    __shared__ unsigned int s[THREADS];
    s[bin] = ad;
    __syncthreads();
    for (int off = THREADS / 2; off >= 1; off >>= 1) {
        if (bin < off) s[bin] += s[bin + off];
        __syncthreads();
    }
    if (bin == 0) atomicAdd(gsum, s[0]);
}

__global__ void finalize_kernel(const unsigned int* __restrict__ gsum,
                                float* __restrict__ out)
{
    double v = (double)(*gsum) /
               ((double)HW_N * (double)ROWS * (double)NB);
    out[0] = (float)v;
}

extern "C" void kernel_launch(void* const* d_in, const int* in_sizes, int n_in,
                              void* d_out, int out_size, void* d_ws, size_t ws_size,
                              hipStream_t stream) {
    const float* out_t = (const float*)d_in[0];
    const float* tgt_t = (const float*)d_in[1];
    unsigned int* partials = (unsigned int*)d_ws;
    unsigned int* gsum = partials + (size_t)SEGS * SUBS * NB;
    float* out = (float*)d_out;

    hipMemsetAsync(gsum, 0, sizeof(unsigned int), stream);

    hist_kernel<<<dim3(SEGS * SUBS), dim3(THREADS), 0, stream>>>(out_t, tgt_t, partials);
    rowdiff_kernel<<<dim3(ROWS), dim3(THREADS), 0, stream>>>(partials, gsum);
    finalize_kernel<<<1, 1, 0, stream>>>(gsum, out);
}

// Round 5
// 392.563 us; speedup vs baseline: 1.0185x; 1.0085x over previous
//
#include <hip/hip_runtime.h>

// HistogramLoss: B=16, C=3, H=W=1024, num_bins=256.
// loss = sum over (48 rows, 256 bins) |c_out - c_tgt| / (HW * 48 * 256).
// Exact integer counts; divide once at the end.
//
// R3 changes vs R2:
//  - explicit register double-buffer (4 float4 in flight) for MLP
//  - 8-way sub-bucketed block histogram h[(bin<<3)|(tid&7)] -> ~2-way
//    bank aliasing (free) instead of 4-5-way conflicts + same-addr RMW
//  - merge 8 sub-copies at block end, non-atomic partial store

#define NB       256
#define HW_N     (1024 * 1024)
#define ROWS     48                  // B*C
#define SEGS     (2 * ROWS)          // 96: tensor*ROWS + row
#define SUBS     16                  // sub-blocks per segment
#define THREADS  256
#define NSUB     8                   // sub-histogram copies per block

// d_ws layout:
//   uint32 partials[SEGS*SUBS][NB]   (1536*256*4 = 1.5 MB)
//   uint32 gsum

__global__ __launch_bounds__(THREADS) void hist_kernel(
    const float* __restrict__ out_t,
    const float* __restrict__ tgt_t,
    unsigned int* __restrict__ partials)
{
    __shared__ unsigned int lh[NB * NSUB];   // 8 KB, [bin][subcopy]
    const int tid = threadIdx.x;
    const int sub_off = tid & (NSUB - 1);    // which sub-copy this lane owns

    #pragma unroll
    for (int i = tid; i < NB * NSUB; i += THREADS) lh[i] = 0u;
    __syncthreads();

    const int blk = blockIdx.x;              // 0 .. SEGS*SUBS-1
    const int seg = blk / SUBS;
    const int sb  = blk % SUBS;
    const float* src = (seg < ROWS) ? out_t : tgt_t;
    const int row = (seg < ROWS) ? seg : (seg - ROWS);

    const int elems = HW_N / SUBS;           // 65536 per block
    const size_t base = (size_t)row * HW_N + (size_t)sb * elems;
    const float4* __restrict__ p = reinterpret_cast<const float4*>(src + base);
    // 16384 float4 per block; 64 float4 per thread; 16 outer iters of 4.

    #define BIN(x) min(max((int)floorf((x) * (float)NB), 0), NB - 1)
    #define ACC(v) do { \
        atomicAdd(&lh[(BIN(v.x) << 3) | sub_off], 1u); \
        atomicAdd(&lh[(BIN(v.y) << 3) | sub_off], 1u); \
        atomicAdd(&lh[(BIN(v.z) << 3) | sub_off], 1u); \
        atomicAdd(&lh[(BIN(v.w) << 3) | sub_off], 1u); \
    } while (0)

    // register double-buffer: prefetch next 4 while processing current 4
    float4 c0 = p[tid];
    float4 c1 = p[tid + 256];
    float4 c2 = p[tid + 512];
    float4 c3 = p[tid + 768];
    #pragma unroll 1
    for (int t = 0; t < 15; ++t) {
        const int i1 = (t + 1) * 1024 + tid;
        float4 n0 = p[i1];
        float4 n1 = p[i1 + 256];
        float4 n2 = p[i1 + 512];
        float4 n3 = p[i1 + 768];
        ACC(c0); ACC(c1); ACC(c2); ACC(c3);
        c0 = n0; c1 = n1; c2 = n2; c3 = n3;
    }
    ACC(c0); ACC(c1); ACC(c2); ACC(c3);
    #undef ACC
    #undef BIN
    __syncthreads();

    // merge the 8 sub-copies; thread t owns bin t (256 threads = 256 bins)
    const uint4* lh4 = reinterpret_cast<const uint4*>(lh);
    uint4 a = lh4[tid * 2];
    uint4 b = lh4[tid * 2 + 1];
    unsigned int c = a.x + a.y + a.z + a.w + b.x + b.y + b.z + b.w;
    partials[(size_t)blk * NB + tid] = c;
}

__global__ __launch_bounds__(THREADS) void rowdiff_kernel(
    const unsigned int* __restrict__ partials,
    unsigned int* __restrict__ gsum)
{
    const int r = blockIdx.x;      // 0..ROWS-1
    const int bin = threadIdx.x;   // one bin per thread
    unsigned int a = 0, b = 0;
    #pragma unroll
    for (int s = 0; s < SUBS; ++s) {
        a += partials[((size_t)(r)        * SUBS + s) * NB + bin];
        b += partials[((size_t)(ROWS + r) * SUBS + s) * NB + bin];
    }
    int d = (int)a - (int)b;
    unsigned int ad = (unsigned int)((d < 0) ? -d : d);

    __shared__ unsigned int s[THREADS];
    s[bin] = ad;
    __syncthreads();
    for (int off = THREADS / 2; off >= 1; off >>= 1) {
        if (bin < off) s[bin] += s[bin + off];
        __syncthreads();
    }
    if (bin == 0) atomicAdd(gsum, s[0]);
}

__global__ void finalize_kernel(const unsigned int* __restrict__ gsum,
                                float* __restrict__ out)
{
    double v = (double)(*gsum) /
               ((double)HW_N * (double)ROWS * (double)NB);
    out[0] = (float)v;
}

extern "C" void kernel_launch(void* const* d_in, const int* in_sizes, int n_in,
                              void* d_out, int out_size, void* d_ws, size_t ws_size,
                              hipStream_t stream) {
    const float* out_t = (const float*)d_in[0];
    const float* tgt_t = (const float*)d_in[1];
    unsigned int* partials = (unsigned int*)d_ws;
    unsigned int* gsum = partials + (size_t)SEGS * SUBS * NB;
    float* out = (float*)d_out;

    hipMemsetAsync(gsum, 0, sizeof(unsigned int), stream);

    hist_kernel<<<dim3(SEGS * SUBS), dim3(THREADS), 0, stream>>>(out_t, tgt_t, partials);
    rowdiff_kernel<<<dim3(ROWS), dim3(THREADS), 0, stream>>>(partials, gsum);
    finalize_kernel<<<1, 1, 0, stream>>>(gsum, out);
}